// Round 2
// baseline (2735.379 us; speedup 1.0000x reference)
//
#include <hip/hip_runtime.h>
#include <hip/hip_bf16.h>
#include <stdint.h>

#define N_NODES 40000
#define M_PAD   40064      // 313 * 128
#define V_DIM   5000
#define K1_PAD  5056       // 79 * 64
#define E_EDGES 1280000
#define B_BATCH 64
#define NCLS    20
#define POOL_BLOCKS 160
#define POOL_NPER   250

typedef __attribute__((ext_vector_type(8))) short bf16x8;
typedef __attribute__((ext_vector_type(4))) float f32x4;

__device__ __forceinline__ unsigned short f2bf(float x) {
    union { float f; unsigned int u; } c; c.f = x;
    unsigned int u = c.u;
    unsigned int r = (u + 0x7FFFu + ((u >> 16) & 1u)) >> 16;  // RNE
    return (unsigned short)r;
}
__device__ __forceinline__ float bf2f(unsigned short b) {
    union { unsigned int u; float f; } c; c.u = ((unsigned int)b) << 16; return c.f;
}
__device__ __forceinline__ unsigned int pk_bf16(float a, float b) {
    __hip_bfloat162 h = __float22bfloat162_rn(make_float2(a, b));  // v_cvt_pk_bf16_f32
    union { __hip_bfloat162 v; unsigned int u; } cv; cv.v = h; return cv.u;
}

// ---------------------------------------------------------------------------
// Coalesced transpose+convert: W [K x N] fp32 -> BT [N x K_pad] bf16 (zero pad)
// grid (ceil(K_pad/64), N/64), 256 threads, 64x64 tiles via LDS.
// ---------------------------------------------------------------------------
__global__ __launch_bounds__(256)
void transpose_cvt(const float* __restrict__ W, unsigned short* __restrict__ BT,
                   int K, int N, int K_pad)
{
    __shared__ float tile[64][65];
    const int t = threadIdx.x;
    const int k0 = blockIdx.x * 64, n0 = blockIdx.y * 64;
    const int tn = t & 63, tk = t >> 6;
#pragma unroll
    for (int r = 0; r < 64; r += 4) {
        int k = k0 + tk + r;
        tile[tk + r][tn] = (k < K) ? W[(size_t)k * N + n0 + tn] : 0.f;
    }
    __syncthreads();
    const int blk = t & 7;
#pragma unroll
    for (int i = 0; i < 2; ++i) {
        int row = (t >> 3) + i * 32;          // n within tile
        uint4 pa;
        pa.x = pk_bf16(tile[blk * 8 + 0][row], tile[blk * 8 + 1][row]);
        pa.y = pk_bf16(tile[blk * 8 + 2][row], tile[blk * 8 + 3][row]);
        pa.z = pk_bf16(tile[blk * 8 + 4][row], tile[blk * 8 + 5][row]);
        pa.w = pk_bf16(tile[blk * 8 + 6][row], tile[blk * 8 + 7][row]);
        *(uint4*)(BT + (size_t)(n0 + row) * K_pad + k0 + blk * 8) = pa;
    }
}

// ---------------------------------------------------------------------------
// bf16 MFMA GEMM, 128x128 tile, BK=64, register prefetch, swizzled LDS.
// A fp32 [rows x K_real] converted in staging (row index clamped to M_clamp).
// BT bf16 [256 x K_pad]. Output: Cf (fp32 +bias) or Cb (bf16), stride 256.
// ---------------------------------------------------------------------------
__global__ __launch_bounds__(256)
void gemm_bf16(const float* __restrict__ A, const unsigned short* __restrict__ BT,
               float* __restrict__ Cf, unsigned short* __restrict__ Cb,
               const float* __restrict__ bias,
               int M_clamp, int K_real, int K_pad)
{
    __shared__ unsigned short As[128 * 64];   // 16 KB
    __shared__ unsigned short Bs[128 * 64];   // 16 KB
    const int m0 = blockIdx.x * 128;
    const int n0 = blockIdx.y * 128;
    const int t = threadIdx.x;
    const int lane = t & 63;
    const int wave = t >> 6;
    const int wr = (wave >> 1) * 64;
    const int wc = (wave & 1) * 64;
    const int lm = lane & 15;
    const int lkq = lane >> 4;                // 0..3
    const int blk = t & 7;                    // k-chunk of 8
    const int r0 = t >> 3;                    // row base 0..31

    float4 ra[8];
    uint4 rb[4];

    auto loadA = [&](int k0) {
        int k = k0 + blk * 8;
        bool valid = (k < K_real);            // K_real % 8 == 0 for all call sites
#pragma unroll
        for (int i = 0; i < 4; ++i) {
            int gr = m0 + r0 + i * 32;
            gr = gr < M_clamp ? gr : M_clamp;
            const float* p = A + (size_t)gr * K_real + k;
            if (valid) { ra[2 * i] = *(const float4*)p; ra[2 * i + 1] = *(const float4*)(p + 4); }
            else       { ra[2 * i] = make_float4(0, 0, 0, 0); ra[2 * i + 1] = make_float4(0, 0, 0, 0); }
        }
    };
    auto loadB = [&](int k0) {
        int k = k0 + blk * 8;
#pragma unroll
        for (int i = 0; i < 4; ++i)
            rb[i] = *(const uint4*)(BT + (size_t)(n0 + r0 + i * 32) * K_pad + k);
    };
    auto stage = [&]() {
#pragma unroll
        for (int i = 0; i < 4; ++i) {
            int row = r0 + i * 32;
            int phys = blk ^ (row & 7);
            uint4 pa;
            pa.x = pk_bf16(ra[2 * i].x, ra[2 * i].y);
            pa.y = pk_bf16(ra[2 * i].z, ra[2 * i].w);
            pa.z = pk_bf16(ra[2 * i + 1].x, ra[2 * i + 1].y);
            pa.w = pk_bf16(ra[2 * i + 1].z, ra[2 * i + 1].w);
            *(uint4*)&As[row * 64 + phys * 8] = pa;
            *(uint4*)&Bs[row * 64 + phys * 8] = rb[i];
        }
    };

    f32x4 acc[4][4];
#pragma unroll
    for (int i = 0; i < 4; i++)
#pragma unroll
        for (int j = 0; j < 4; j++) {
            acc[i][j][0] = 0.f; acc[i][j][1] = 0.f; acc[i][j][2] = 0.f; acc[i][j][3] = 0.f;
        }

    loadA(0); loadB(0);
    const int nkt = K_pad >> 6;
    for (int kt = 0; kt < nkt; ++kt) {
        stage();
        __syncthreads();
        if (kt + 1 < nkt) { loadA((kt + 1) << 6); loadB((kt + 1) << 6); }  // in flight over MFMA
#pragma unroll
        for (int kh = 0; kh < 2; ++kh) {
            bf16x8 af[4], bfr[4];
#pragma unroll
            for (int i = 0; i < 4; ++i) {
                int row = wr + i * 16 + lm;
                int phys = (kh * 4 + lkq) ^ (row & 7);
                af[i] = *(const bf16x8*)&As[row * 64 + phys * 8];
            }
#pragma unroll
            for (int j = 0; j < 4; ++j) {
                int row = wc + j * 16 + lm;
                int phys = (kh * 4 + lkq) ^ (row & 7);
                bfr[j] = *(const bf16x8*)&Bs[row * 64 + phys * 8];
            }
#pragma unroll
            for (int i = 0; i < 4; ++i)
#pragma unroll
                for (int j = 0; j < 4; ++j)
                    acc[i][j] = __builtin_amdgcn_mfma_f32_16x16x32_bf16(af[i], bfr[j], acc[i][j], 0, 0, 0);
        }
        __syncthreads();
    }

    const int lrow = (lane >> 4) * 4;
#pragma unroll
    for (int i = 0; i < 4; ++i) {
        int rowb = m0 + wr + i * 16 + lrow;
#pragma unroll
        for (int j = 0; j < 4; ++j) {
            int col = n0 + wc + j * 16 + lm;
            if (Cf) {
                float badd = bias ? bias[col] : 0.f;
#pragma unroll
                for (int r = 0; r < 4; ++r)
                    Cf[(size_t)(rowb + r) * 256 + col] = acc[i][j][r] + badd;
            } else {
#pragma unroll
                for (int r = 0; r < 4; ++r)
                    Cb[(size_t)(rowb + r) * 256 + col] = f2bf(acc[i][j][r]);
            }
        }
    }
}

// ---------------------------------------------------------------------------
// CSR build
// ---------------------------------------------------------------------------
__global__ void deg_init(int* __restrict__ deg, int n) {
    int i = blockIdx.x * 256 + threadIdx.x;
    if (i < n) deg[i] = 1;                   // self-loop
}
__global__ void count_kernel(const int* __restrict__ ei, int* __restrict__ deg, int E) {
    int e = blockIdx.x * 256 + threadIdx.x;
    if (e < E) atomicAdd(&deg[ei[E + e]], 1);
}
__global__ void scan_kernel(const int* __restrict__ deg, int* __restrict__ row_start, int n) {
    __shared__ int sws[16];
    __shared__ int carry_s;
    const int t = threadIdx.x, lane = t & 63, w = t >> 6;
    if (t == 0) carry_s = 0;
    __syncthreads();
    for (int base = 0; base < n; base += 1024) {
        int i = base + t;
        int v = (i < n) ? deg[i] : 0;
        int incl = v;
#pragma unroll
        for (int off = 1; off < 64; off <<= 1) {
            int y = __shfl_up(incl, off, 64);
            if (lane >= off) incl += y;
        }
        if (lane == 63) sws[w] = incl;
        __syncthreads();
        if (t < 16) {
            int x = sws[t];
#pragma unroll
            for (int off = 1; off < 16; off <<= 1) {
                int y = __shfl_up(x, off, 16);
                if ((t & 15) >= off) x += y;
            }
            sws[t] = x;
        }
        __syncthreads();
        int c = carry_s;
        int waveoff = (w > 0) ? sws[w - 1] : 0;
        if (i < n) row_start[i] = c + waveoff + incl - v;   // exclusive
        __syncthreads();
        if (t == 0) carry_s = c + sws[15];
        __syncthreads();
    }
    if (t == 0) row_start[n] = carry_s;
}
__global__ void selfloop_kernel(const int* __restrict__ row_start, int* __restrict__ cursor,
                                int* __restrict__ nbr, int n) {
    int i = blockIdx.x * 256 + threadIdx.x;
    if (i < n) { int rs = row_start[i]; nbr[rs] = i; cursor[i] = rs + 1; }
}
__global__ void scatter_kernel(const int* __restrict__ ei, int* __restrict__ cursor,
                               int* __restrict__ nbr, int E) {
    int e = blockIdx.x * 256 + threadIdx.x;
    if (e < E) {
        int s = ei[e], d = ei[E + e];
        int pos = atomicAdd(&cursor[d], 1);
        nbr[pos] = s;
    }
}

// ---------------------------------------------------------------------------
// Pooling: atomic-free two-stage (LDS per-block accumulation, thread-exclusive
// columns), then tiny reduce across POOL_BLOCKS partials.
// ---------------------------------------------------------------------------
__global__ void batch_count(const int* __restrict__ batch, float* __restrict__ cnt, int n) {
    int i = blockIdx.x * 256 + threadIdx.x;
    if (i < n) atomicAdd(&cnt[batch[i]], 1.f);
}
__global__ __launch_bounds__(256)
void pool_partial(const float* __restrict__ x, const int* __restrict__ batch,
                  float* __restrict__ partial)
{
    __shared__ float acc[64 * 256];          // 64 KB
    const int t = threadIdx.x;
#pragma unroll
    for (int i = 0; i < 64; ++i) acc[i * 256 + t] = 0.f;
    int nbeg = blockIdx.x * POOL_NPER;
    int nend = nbeg + POOL_NPER; if (nend > N_NODES) nend = N_NODES;
    for (int node = nbeg; node < nend; ++node) {
        int b = batch[node];
        acc[b * 256 + t] += x[(size_t)node * 256 + t];   // thread t owns column t
    }
    float* dst = partial + (size_t)blockIdx.x * 64 * 256;
#pragma unroll 4
    for (int i = 0; i < 64; ++i) dst[i * 256 + t] = acc[i * 256 + t];
}
__global__ void pool_reduce(const float* __restrict__ partial, float* __restrict__ sums) {
    int b = blockIdx.x, t = threadIdx.x;
    float s = 0.f;
    for (int k = 0; k < POOL_BLOCKS; ++k) s += partial[(size_t)k * 16384 + b * 256 + t];
    sums[b * 256 + t] = s;
}

// ---------------------------------------------------------------------------
// Attention scores from bf16 h
// ---------------------------------------------------------------------------
template <int H, int C>
__global__ __launch_bounds__(256)
void attn_scores(const unsigned short* __restrict__ hb, const float* __restrict__ a_src,
                 const float* __restrict__ a_dst, float* __restrict__ s_src,
                 float* __restrict__ s_dst)
{
    const int node = blockIdx.x;
    const int t = threadIdx.x;
    float hv = bf2f(hb[(size_t)node * 256 + t]);
    float ps = hv * a_src[t];
    float pd = hv * a_dst[t];
#pragma unroll
    for (int off = C / 2; off >= 1; off >>= 1) {
        ps += __shfl_down(ps, off, 64);
        pd += __shfl_down(pd, off, 64);
    }
    if ((t & (C - 1)) == 0) {
        s_src[node * H + t / C] = ps;
        s_dst[node * H + t / C] = pd;
    }
}

// ---------------------------------------------------------------------------
// Fused GAT aggregate (bf16 h gather, pipelined) + bias + elu + residual + LN
// ---------------------------------------------------------------------------
template <int H, int C>
__global__ __launch_bounds__(256)
void gat_kernel(const unsigned short* __restrict__ hb, const float* __restrict__ s_src,
                const float* __restrict__ s_dst, const int* __restrict__ row_start,
                const int* __restrict__ nbr, const float* __restrict__ bias,
                const float* __restrict__ gamma, const float* __restrict__ beta,
                const float* __restrict__ x_in, float* __restrict__ x_out)
{
    const int node = blockIdx.x;
    const int t = threadIdx.x;
    const int head = t / C;
    const float sd = s_dst[node * H + head];
    const int beg = row_start[node], end = row_start[node + 1];

    float m = -3.4e38f, z = 0.f, acc = 0.f;
    int s0 = nbr[beg];
    float sr_n = s_src[s0 * H + head];
    float hv_n = bf2f(hb[(size_t)s0 * 256 + t]);
    for (int p = beg; p < end; ++p) {
        float sr = sr_n, hv = hv_n;
        if (p + 1 < end) {
            int s1 = nbr[p + 1];
            sr_n = s_src[s1 * H + head];
            hv_n = bf2f(hb[(size_t)s1 * 256 + t]);
        }
        float e = sr + sd;
        e = (e > 0.f) ? e : 0.2f * e;          // leaky_relu 0.2
        float mn = fmaxf(m, e);
        float sc = __expf(m - mn);
        float pe = __expf(e - mn);
        z = z * sc + pe;
        acc = acc * sc + pe * hv;
        m = mn;
    }
    float v = acc / z + bias[t];
    v = (v > 0.f) ? v : (__expf(v) - 1.f);     // elu
    v += x_in[(size_t)node * 256 + t];         // residual

    __shared__ float sbuf[256];
    sbuf[t] = v; __syncthreads();
    for (int s2 = 128; s2 > 0; s2 >>= 1) { if (t < s2) sbuf[t] += sbuf[t + s2]; __syncthreads(); }
    float mu = sbuf[0] * (1.f / 256.f);
    __syncthreads();
    float d = v - mu;
    sbuf[t] = d * d; __syncthreads();
    for (int s2 = 128; s2 > 0; s2 >>= 1) { if (t < s2) sbuf[t] += sbuf[t + s2]; __syncthreads(); }
    float var = sbuf[0] * (1.f / 256.f);
    x_out[(size_t)node * 256 + t] = d * rsqrtf(var + 1e-5f) * gamma[t] + beta[t];
}

// ---------------------------------------------------------------------------
// Head MLP: one block per batch row
// ---------------------------------------------------------------------------
__global__ __launch_bounds__(256)
void mlp_head(const float* __restrict__ xg_sum, const float* __restrict__ xs_sum,
              const float* __restrict__ cnt,
              const float* __restrict__ Wf, const float* __restrict__ bfv,
              const float* __restrict__ Wc1, const float* __restrict__ bc1,
              const float* __restrict__ Wc2, const float* __restrict__ bc2,
              float* __restrict__ out)
{
    const int b = blockIdx.x;
    const int t = threadIdx.x;
    __shared__ float xc[512];
    __shared__ float fs[256];
    __shared__ float gs[128];
    __shared__ float logits[NCLS];
    float c = fmaxf(cnt[b], 1.f);
    xc[t]       = xg_sum[b * 256 + t] / c;
    xc[256 + t] = xs_sum[b * 256 + t] / c;
    __syncthreads();
    float a = bfv[t];
    for (int i = 0; i < 512; i++) a += xc[i] * Wf[i * 256 + t];
    fs[t] = fmaxf(a, 0.f);
    __syncthreads();
    if (t < 128) {
        float a1 = bc1[t];
        for (int i = 0; i < 256; i++) a1 += fs[i] * Wc1[i * 128 + t];
        gs[t] = fmaxf(a1, 0.f);
    }
    __syncthreads();
    if (t < NCLS) {
        float a2 = bc2[t];
        for (int i = 0; i < 128; i++) a2 += gs[i] * Wc2[i * NCLS + t];
        logits[t] = a2;
    }
    __syncthreads();
    if (t < NCLS) {
        float mx = -3.4e38f;
        for (int i = 0; i < NCLS; i++) mx = fmaxf(mx, logits[i]);
        float s = 0.f;
        for (int i = 0; i < NCLS; i++) s += expf(logits[i] - mx);
        out[b * NCLS + t] = logits[t] - mx - logf(s);
    }
}

// ---------------------------------------------------------------------------
extern "C" void kernel_launch(void* const* d_in, const int* in_sizes, int n_in,
                              void* d_out, int out_size, void* d_ws, size_t ws_size,
                              hipStream_t stream)
{
    const float* x      = (const float*)d_in[0];
    const int*   ei     = (const int*)d_in[1];
    const int*   batch  = (const int*)d_in[2];
    const float* W_in   = (const float*)d_in[3];
    const float* b_in   = (const float*)d_in[4];
    const float* W1     = (const float*)d_in[5];
    const float* att_s1 = (const float*)d_in[6];
    const float* att_d1 = (const float*)d_in[7];
    const float* b1     = (const float*)d_in[8];
    const float* g1     = (const float*)d_in[9];
    const float* be1    = (const float*)d_in[10];
    const float* W2     = (const float*)d_in[11];
    const float* att_s2 = (const float*)d_in[12];
    const float* att_d2 = (const float*)d_in[13];
    const float* b2     = (const float*)d_in[14];
    const float* g2     = (const float*)d_in[15];
    const float* be2    = (const float*)d_in[16];
    const float* Wf     = (const float*)d_in[17];
    const float* bfv    = (const float*)d_in[18];
    const float* Wc1    = (const float*)d_in[19];
    const float* bc1    = (const float*)d_in[20];
    const float* Wc2    = (const float*)d_in[21];
    const float* bc2    = (const float*)d_in[22];
    float* out = (float*)d_out;

    char* ws = (char*)d_ws;
    size_t off = 0;
    auto alloc = [&](size_t bytes) -> char* {
        char* p = ws + off;
        off += (bytes + 255) & ~(size_t)255;
        return p;
    };
    float* x0 = (float*)alloc((size_t)M_PAD * 256 * 4);
    float* x1 = (float*)alloc((size_t)M_PAD * 256 * 4);
    unsigned short* hb = (unsigned short*)alloc((size_t)M_PAD * 256 * 2);
    unsigned short* BTin = (unsigned short*)alloc((size_t)256 * K1_PAD * 2);
    unsigned short* BT1  = (unsigned short*)alloc((size_t)256 * 256 * 2);
    unsigned short* BT2  = (unsigned short*)alloc((size_t)256 * 256 * 2);
    float* s_src = (float*)alloc((size_t)N_NODES * 8 * 4);
    float* s_dst = (float*)alloc((size_t)N_NODES * 8 * 4);
    int* deg       = (int*)alloc((size_t)N_NODES * 4);
    int* row_start = (int*)alloc((size_t)(N_NODES + 1) * 4);
    int* cursor    = (int*)alloc((size_t)N_NODES * 4);
    int* nbr       = (int*)alloc((size_t)(E_EDGES + N_NODES) * 4);
    float* partial = (float*)alloc((size_t)POOL_BLOCKS * 64 * 256 * 4);
    float* xs_sum  = (float*)alloc(64 * 256 * 4);
    float* xg_sum  = (float*)alloc(64 * 256 * 4);
    float* cnt     = (float*)alloc(64 * 4);
    float* x2 = x0;   // x0 buffer reused for x2 (dead after gat1 + skip pool)

    hipMemsetAsync(cnt, 0, 64 * 4, stream);

    // weight prep + CSR build
    transpose_cvt<<<dim3(K1_PAD / 64, 4), 256, 0, stream>>>(W_in, BTin, V_DIM, 256, K1_PAD);
    transpose_cvt<<<dim3(4, 4), 256, 0, stream>>>(W1, BT1, 256, 256, 256);
    transpose_cvt<<<dim3(4, 4), 256, 0, stream>>>(W2, BT2, 256, 256, 256);
    deg_init<<<(N_NODES + 255) / 256, 256, 0, stream>>>(deg, N_NODES);
    count_kernel<<<(E_EDGES + 255) / 256, 256, 0, stream>>>(ei, deg, E_EDGES);
    scan_kernel<<<1, 1024, 0, stream>>>(deg, row_start, N_NODES);
    selfloop_kernel<<<(N_NODES + 255) / 256, 256, 0, stream>>>(row_start, cursor, nbr, N_NODES);
    scatter_kernel<<<(E_EDGES + 255) / 256, 256, 0, stream>>>(ei, cursor, nbr, E_EDGES);
    batch_count<<<(N_NODES + 255) / 256, 256, 0, stream>>>(batch, cnt, N_NODES);

    // input projection (fp32 out, +bias), then skip pooling
    gemm_bf16<<<dim3(313, 2), 256, 0, stream>>>(x, BTin, x0, nullptr, b_in, N_NODES - 1, V_DIM, K1_PAD);
    pool_partial<<<POOL_BLOCKS, 256, 0, stream>>>(x0, batch, partial);
    pool_reduce<<<B_BATCH, 256, 0, stream>>>(partial, xs_sum);

    // conv1 (h in bf16)
    gemm_bf16<<<dim3(313, 2), 256, 0, stream>>>(x0, BT1, nullptr, hb, nullptr, M_PAD - 1, 256, 256);
    attn_scores<8, 32><<<N_NODES, 256, 0, stream>>>(hb, att_s1, att_d1, s_src, s_dst);
    gat_kernel<8, 32><<<N_NODES, 256, 0, stream>>>(hb, s_src, s_dst, row_start, nbr,
                                                   b1, g1, be1, x0, x1);
    // conv2
    gemm_bf16<<<dim3(313, 2), 256, 0, stream>>>(x1, BT2, nullptr, hb, nullptr, M_PAD - 1, 256, 256);
    attn_scores<4, 64><<<N_NODES, 256, 0, stream>>>(hb, att_s2, att_d2, s_src, s_dst);
    gat_kernel<4, 64><<<N_NODES, 256, 0, stream>>>(hb, s_src, s_dst, row_start, nbr,
                                                   b2, g2, be2, x1, x2);

    // global pooling + head
    pool_partial<<<POOL_BLOCKS, 256, 0, stream>>>(x2, batch, partial);
    pool_reduce<<<B_BATCH, 256, 0, stream>>>(partial, xg_sum);
    mlp_head<<<B_BATCH, 256, 0, stream>>>(xg_sum, xs_sum, cnt, Wf, bfv, Wc1, bc1, Wc2, bc2, out);
}